// Round 1
// baseline (744.255 us; speedup 1.0000x reference)
//
#include <hip/hip_runtime.h>

// ---------------- workspace layout (bytes) ----------------
// ctx      : 6*4096*512 f32  = 50,331,648
// head_out : 24576*300 f32   = 29,491,200
// prop_out : 8192*300 f32    =  9,830,400
// nidx     : 24576 i32       =     98,304
// pidx     : 8192 i32        =     32,768
#define CTX_OFF   0ULL
#define HEAD_OFF  50331648ULL
#define PROP_OFF  79822848ULL
#define NIDX_OFF  89653248ULL
#define PIDX_OFF  89751552ULL

// =============================================================
// Kernel A: gather + online-softmax attention -> context (fp32)
// one wave (64 lanes) per (head h in [0,6), row b in [0,4096))
// =============================================================
__global__ __launch_bounds__(256) void attend_kernel(
    const int* __restrict__ inputs,        // (4096,2,32)
    const int* __restrict__ inputs_prop,   // (4096,2,3,32)
    const float* __restrict__ emb,         // (100000,512)
    const float* __restrict__ v,           // (31,)
    float* __restrict__ ctx,               // (6,4096,512)
    int* __restrict__ nidx,                // (6,4096)
    int* __restrict__ pidx)                // (2,4096)
{
    int w    = blockIdx.x * 4 + (threadIdx.x >> 6);
    int lane = threadIdx.x & 63;
    int h = w >> 12;         // 0..5
    int b = w & 4095;

    int base, i = 0;
    const int* ip;
    if (h < 2) { base = (b * 2 + h) * 32; ip = inputs; }
    else {
        i = (h - 2) >> 1;
        int s = 1 + ((h - 2) & 1);
        base = ((b * 2 + i) * 3 + s) * 32;
        ip = inputs_prop;
    }

    int myidx = 0;
    if (lane < 32) myidx = ip[base + lane];
    int idx0 = __shfl(myidx, 0);
    if (lane == 0) {
        nidx[w] = idx0;
        if (h == 2 || h == 4) pidx[i * 4096 + b] = inputs_prop[((b * 2 + i) * 3) * 32];
    }

    const float4* emb4 = (const float4*)emb;
    float4 n0 = emb4[(size_t)idx0 * 128 + lane];
    float4 n1 = emb4[(size_t)idx0 * 128 + 64 + lane];

    float m = -3.0e38f, den = 0.0f;
    float4 c0 = make_float4(0.f, 0.f, 0.f, 0.f);
    float4 c1 = make_float4(0.f, 0.f, 0.f, 0.f);

    for (int j = 1; j < 32; ++j) {
        int ij = __shfl(myidx, j);
        float4 e0 = emb4[(size_t)ij * 128 + lane];
        float4 e1 = emb4[(size_t)ij * 128 + 64 + lane];
        float p = e0.x * n0.x + e0.y * n0.y + e0.z * n0.z + e0.w * n0.w
                + e1.x * n1.x + e1.y * n1.y + e1.z * n1.z + e1.w * n1.w;
        #pragma unroll
        for (int d = 1; d < 64; d <<= 1) p += __shfl_xor(p, d);

        float s  = (p != 0.0f) ? p : -9999.0f;   // mask: scores==0 -> -NEG
        float mn = fmaxf(m, s);
        float scale = expf(m - mn);
        float e  = expf(s - mn);
        den = den * scale + e;
        float we = v[j - 1] * e;
        c0.x = c0.x * scale + we * e0.x;  c0.y = c0.y * scale + we * e0.y;
        c0.z = c0.z * scale + we * e0.z;  c0.w = c0.w * scale + we * e0.w;
        c1.x = c1.x * scale + we * e1.x;  c1.y = c1.y * scale + we * e1.y;
        c1.z = c1.z * scale + we * e1.z;  c1.w = c1.w * scale + we * e1.w;
        m = mn;
    }
    float inv = 1.0f / den;
    float4* ctx4 = (float4*)ctx;
    ctx4[(size_t)w * 128 + lane]      = make_float4(c0.x*inv, c0.y*inv, c0.z*inv, c0.w*inv);
    ctx4[(size_t)w * 128 + 64 + lane] = make_float4(c1.x*inv, c1.y*inv, c1.z*inv, c1.w*inv);
}

// =============================================================
// Kernel B: head GEMM  Y[24576,300] = [node|ctx] @ W_out^T + b
// node part re-gathered from emb (L3-resident) via nidx.
// 128x64 tile, BK=16, 256 threads, 8x4 per-thread microtile.
// =============================================================
#define AST 132
#define BST 68

__global__ __launch_bounds__(256) void gemm_head_kernel(
    const float* __restrict__ emb,
    const float* __restrict__ ctx,     // (24576,512)
    const int*  __restrict__ nidx,     // (24576,)
    const float* __restrict__ W,       // (300,1024)
    const float* __restrict__ bias,    // (300,)
    float* __restrict__ out)           // (24576,300)
{
    __shared__ float As[16 * AST];
    __shared__ float Bs[16 * BST];
    __shared__ int   sN[128];

    int t  = threadIdx.x;
    int m0 = blockIdx.y * 128;
    int n0 = blockIdx.x * 64;
    if (t < 128) sN[t] = nidx[m0 + t];
    __syncthreads();

    int tx = t & 15, ty = t >> 4;
    float acc[8][4];
    #pragma unroll
    for (int r = 0; r < 8; ++r)
        #pragma unroll
        for (int c = 0; c < 4; ++c) acc[r][c] = 0.0f;

    const float4* emb4 = (const float4*)emb;
    const float4* ctx4 = (const float4*)ctx;
    const float4* W4   = (const float4*)W;

    for (int k0 = 0; k0 < 1024; k0 += 16) {
        #pragma unroll
        for (int it = 0; it < 2; ++it) {
            int idx = t + 256 * it;
            int ml  = idx >> 2;
            int kc  = (idx & 3) * 4;
            int k   = k0 + kc;
            float4 f;
            if (k < 512) f = emb4[(size_t)sN[ml] * 128 + (k >> 2)];
            else         f = ctx4[(size_t)(m0 + ml) * 128 + ((k - 512) >> 2)];
            As[(kc + 0) * AST + ml] = f.x;
            As[(kc + 1) * AST + ml] = f.y;
            As[(kc + 2) * AST + ml] = f.z;
            As[(kc + 3) * AST + ml] = f.w;
        }
        {
            int nl = t >> 2;
            int kc = (t & 3) * 4;
            int gn = n0 + nl;
            float4 f = make_float4(0.f, 0.f, 0.f, 0.f);
            if (gn < 300) f = W4[(size_t)gn * 256 + ((k0 + kc) >> 2)];
            Bs[(kc + 0) * BST + nl] = f.x;
            Bs[(kc + 1) * BST + nl] = f.y;
            Bs[(kc + 2) * BST + nl] = f.z;
            Bs[(kc + 3) * BST + nl] = f.w;
        }
        __syncthreads();
        #pragma unroll
        for (int kk = 0; kk < 16; ++kk) {
            float4 a0 = *(const float4*)&As[kk * AST + ty * 8];
            float4 a1 = *(const float4*)&As[kk * AST + ty * 8 + 4];
            float4 bb = *(const float4*)&Bs[kk * BST + tx * 4];
            float a[8] = {a0.x, a0.y, a0.z, a0.w, a1.x, a1.y, a1.z, a1.w};
            float bv[4] = {bb.x, bb.y, bb.z, bb.w};
            #pragma unroll
            for (int r = 0; r < 8; ++r)
                #pragma unroll
                for (int c = 0; c < 4; ++c)
                    acc[r][c] += a[r] * bv[c];
        }
        __syncthreads();
    }

    #pragma unroll
    for (int r = 0; r < 8; ++r) {
        int gm = m0 + ty * 8 + r;
        #pragma unroll
        for (int c = 0; c < 4; ++c) {
            int gn = n0 + tx * 4 + c;
            if (gn < 300) out[(size_t)gm * 300 + gn] = acc[r][c] + bias[gn];
        }
    }
}

// =============================================================
// Kernel C: prop GEMM  P[8192,300] = [dom|rng|prp] @ W_prop^T + b
// K=1112 (300|300|512), padded to 1120 with zero-fill.
// =============================================================
__global__ __launch_bounds__(256) void gemm_prop_kernel(
    const float* __restrict__ head_out, // (24576,300)
    const int*  __restrict__ pidx,      // (2,4096)
    const float* __restrict__ emb,
    const float* __restrict__ W,        // (300,1112)
    const float* __restrict__ bias,     // (300,)
    float* __restrict__ out)            // (8192,300)
{
    __shared__ float As[16 * AST];
    __shared__ float Bs[16 * BST];
    __shared__ int sDom[128], sRng[128], sPid[128];

    int t  = threadIdx.x;
    int m0 = blockIdx.y * 128;
    int n0 = blockIdx.x * 64;
    if (t < 128) {
        int m = m0 + t;
        int i = m >> 12, b = m & 4095;
        sDom[t] = ((2 + 2 * i) * 4096 + b) * 300;
        sRng[t] = ((3 + 2 * i) * 4096 + b) * 300;
        sPid[t] = pidx[i * 4096 + b];
    }
    __syncthreads();

    int tx = t & 15, ty = t >> 4;
    float acc[8][4];
    #pragma unroll
    for (int r = 0; r < 8; ++r)
        #pragma unroll
        for (int c = 0; c < 4; ++c) acc[r][c] = 0.0f;

    for (int k0 = 0; k0 < 1120; k0 += 16) {
        #pragma unroll
        for (int it = 0; it < 2; ++it) {
            int idx = t + 256 * it;
            int ml  = idx >> 2;
            int kc  = (idx & 3) * 4;
            #pragma unroll
            for (int j = 0; j < 4; ++j) {
                int k = k0 + kc + j;
                float val;
                if      (k < 300)  val = head_out[sDom[ml] + k];
                else if (k < 600)  val = head_out[sRng[ml] + k - 300];
                else if (k < 1112) val = emb[(size_t)sPid[ml] * 512 + (k - 600)];
                else               val = 0.0f;
                As[(kc + j) * AST + ml] = val;
            }
        }
        {
            int nl = t >> 2;
            int kc = (t & 3) * 4;
            int gn = n0 + nl;
            #pragma unroll
            for (int j = 0; j < 4; ++j) {
                int k = k0 + kc + j;
                float val = (gn < 300 && k < 1112) ? W[(size_t)gn * 1112 + k] : 0.0f;
                Bs[(kc + j) * BST + nl] = val;
            }
        }
        __syncthreads();
        #pragma unroll
        for (int kk = 0; kk < 16; ++kk) {
            float4 a0 = *(const float4*)&As[kk * AST + ty * 8];
            float4 a1 = *(const float4*)&As[kk * AST + ty * 8 + 4];
            float4 bb = *(const float4*)&Bs[kk * BST + tx * 4];
            float a[8] = {a0.x, a0.y, a0.z, a0.w, a1.x, a1.y, a1.z, a1.w};
            float bv[4] = {bb.x, bb.y, bb.z, bb.w};
            #pragma unroll
            for (int r = 0; r < 8; ++r)
                #pragma unroll
                for (int c = 0; c < 4; ++c)
                    acc[r][c] += a[r] * bv[c];
        }
        __syncthreads();
    }

    #pragma unroll
    for (int r = 0; r < 8; ++r) {
        int gm = m0 + ty * 8 + r;
        #pragma unroll
        for (int c = 0; c < 4; ++c) {
            int gn = n0 + tx * 4 + c;
            if (gn < 300) out[(size_t)gm * 300 + gn] = acc[r][c] + bias[gn];
        }
    }
}

// =============================================================
// Kernel D: cosines -> d_out[0:4096]=x_ent, [4096:8192]=x_prop
// one wave per output
// =============================================================
__global__ __launch_bounds__(256) void cosine_kernel(
    const float* __restrict__ head_out,  // (24576,300)
    const float* __restrict__ prop_out,  // (8192,300)
    float* __restrict__ out)             // (8192,)
{
    int w    = blockIdx.x * 4 + (threadIdx.x >> 6);
    int lane = threadIdx.x & 63;
    const float *a, *b;
    if (w < 4096) {
        a = head_out + (size_t)w * 300;
        b = head_out + (size_t)(4096 + w) * 300;
    } else {
        int b2 = w - 4096;
        a = prop_out + (size_t)b2 * 300;
        b = prop_out + (size_t)(4096 + b2) * 300;
    }
    float ab = 0.f, aa = 0.f, bb = 0.f;
    for (int tt = lane; tt < 300; tt += 64) {
        float av = a[tt], bv = b[tt];
        ab += av * bv; aa += av * av; bb += bv * bv;
    }
    #pragma unroll
    for (int d = 1; d < 64; d <<= 1) {
        ab += __shfl_xor(ab, d);
        aa += __shfl_xor(aa, d);
        bb += __shfl_xor(bb, d);
    }
    if (lane == 0) {
        float na = fmaxf(sqrtf(aa), 1e-8f);
        float nb = fmaxf(sqrtf(bb), 1e-8f);
        out[w] = ab / (na * nb);
    }
}

extern "C" void kernel_launch(void* const* d_in, const int* in_sizes, int n_in,
                              void* d_out, int out_size, void* d_ws, size_t ws_size,
                              hipStream_t stream) {
    const int*   inputs      = (const int*)d_in[0];
    const int*   inputs_prop = (const int*)d_in[1];
    const float* emb         = (const float*)d_in[2];
    const float* W_out       = (const float*)d_in[3];
    const float* b_out       = (const float*)d_in[4];
    const float* v           = (const float*)d_in[5];
    const float* W_prop      = (const float*)d_in[6];
    const float* b_prop      = (const float*)d_in[7];
    float* out = (float*)d_out;

    char* ws = (char*)d_ws;
    float* ctx      = (float*)(ws + CTX_OFF);
    float* head_out = (float*)(ws + HEAD_OFF);
    float* prop_out = (float*)(ws + PROP_OFF);
    int*   nidx     = (int*)(ws + NIDX_OFF);
    int*   pidx     = (int*)(ws + PIDX_OFF);

    attend_kernel<<<6144, 256, 0, stream>>>(inputs, inputs_prop, emb, v, ctx, nidx, pidx);
    gemm_head_kernel<<<dim3(5, 192), 256, 0, stream>>>(emb, ctx, nidx, W_out, b_out, head_out);
    gemm_prop_kernel<<<dim3(5, 64), 256, 0, stream>>>(head_out, pidx, emb, W_prop, b_prop, prop_out);
    cosine_kernel<<<2048, 256, 0, stream>>>(head_out, prop_out, out);
}

// Round 2
// 399.415 us; speedup vs baseline: 1.8634x; 1.8634x over previous
//
#include <hip/hip_runtime.h>

typedef short  s16x8 __attribute__((ext_vector_type(8)));
typedef float  f32x4 __attribute__((ext_vector_type(4)));

// ---------------- workspace layout (bytes) ----------------
// Ah  : 24576*1024 bf16 = 50,331,648      (head A hi: [node|ctx])
// Al  : same                              (head A lo)
// Aph : 8192*1152 bf16  = 18,874,368      (prop A hi: [dom|rng|prp|pad])
// Apl : same
// Bh/Bl   : 320*1024 bf16 = 655,360 each  (W_out split, padded rows)
// Bph/Bpl : 320*1152 bf16 = 737,280 each  (W_prop split, padded)
// head_out: 8192*300 f32  = 9,830,400     (ent heads only, fp32 for cosine)
// prop_out: 8192*300 f32  = 9,830,400
#define AH_OFF    0ULL
#define AL_OFF    50331648ULL
#define APH_OFF   100663296ULL
#define APL_OFF   119537664ULL
#define BH_OFF    138412032ULL
#define BL_OFF    139067392ULL
#define BPH_OFF   139722752ULL
#define BPL_OFF   140460032ULL
#define HEAD_OFF  141197312ULL
#define PROP_OFF  151027712ULL   // total 160,858,112

// ---------- fp32 -> bf16 hi/lo split (RNE both) ----------
__device__ __forceinline__ void split2(float x, unsigned short& h, unsigned short& l) {
    unsigned u  = __float_as_uint(x);
    unsigned hb = (u + 0x7FFFu + ((u >> 16) & 1u)) >> 16;
    float hf = __uint_as_float(hb << 16);
    float lf = x - hf;
    unsigned ul = __float_as_uint(lf);
    unsigned lb = (ul + 0x7FFFu + ((ul >> 16) & 1u)) >> 16;
    h = (unsigned short)hb; l = (unsigned short)lb;
}

__device__ __forceinline__ void split_store4(unsigned short* ph, unsigned short* pl, float4 f) {
    ushort4 h, l;
    split2(f.x, h.x, l.x); split2(f.y, h.y, l.y);
    split2(f.z, h.z, l.z); split2(f.w, h.w, l.w);
    *(ushort4*)ph = h; *(ushort4*)pl = l;
}

__device__ __forceinline__ void gload16(const unsigned short* g, unsigned short* l) {
    __builtin_amdgcn_global_load_lds(
        (const __attribute__((address_space(1))) unsigned int*)g,
        (__attribute__((address_space(3))) unsigned int*)l, 16, 0, 0);
}

// =============================================================
// Kernel A: gather + online-softmax attention.
// Writes head-GEMM A panel (node|ctx) as bf16 hi/lo, plus the
// prp slice (+zero pad) of the prop-GEMM A panel.
// one wave per (head h in [0,6), row b in [0,4096))
// =============================================================
__global__ __launch_bounds__(256) void attend_kernel(
    const int* __restrict__ inputs,        // (4096,2,32)
    const int* __restrict__ inputs_prop,   // (4096,2,3,32)
    const float* __restrict__ emb,         // (100000,512)
    const float* __restrict__ v,           // (31,)
    unsigned short* __restrict__ Ah, unsigned short* __restrict__ Al,
    unsigned short* __restrict__ Aph, unsigned short* __restrict__ Apl)
{
    int w    = blockIdx.x * 4 + (threadIdx.x >> 6);
    int lane = threadIdx.x & 63;
    int h = w >> 12;         // 0..5
    int b = w & 4095;

    int base, i = 0;
    const int* ip;
    if (h < 2) { base = (b * 2 + h) * 32; ip = inputs; }
    else {
        i = (h - 2) >> 1;
        int s = 1 + ((h - 2) & 1);
        base = ((b * 2 + i) * 3 + s) * 32;
        ip = inputs_prop;
    }

    int myidx = 0;
    if (lane < 32) myidx = ip[base + lane];
    int idx0 = __shfl(myidx, 0);

    const float4* emb4 = (const float4*)emb;
    float4 n0 = emb4[(size_t)idx0 * 128 + lane];
    float4 n1 = emb4[(size_t)idx0 * 128 + 64 + lane];

    float m = -3.0e38f, den = 0.0f;
    float4 c0 = make_float4(0.f, 0.f, 0.f, 0.f);
    float4 c1 = make_float4(0.f, 0.f, 0.f, 0.f);

    for (int j = 1; j < 32; ++j) {
        int ij = __shfl(myidx, j);
        float4 e0 = emb4[(size_t)ij * 128 + lane];
        float4 e1 = emb4[(size_t)ij * 128 + 64 + lane];
        float p = e0.x * n0.x + e0.y * n0.y + e0.z * n0.z + e0.w * n0.w
                + e1.x * n1.x + e1.y * n1.y + e1.z * n1.z + e1.w * n1.w;
        #pragma unroll
        for (int d = 1; d < 64; d <<= 1) p += __shfl_xor(p, d);

        float s  = (p != 0.0f) ? p : -9999.0f;   // mask: scores==0 -> -NEG
        float mn = fmaxf(m, s);
        float scale = expf(m - mn);
        float e  = expf(s - mn);
        den = den * scale + e;
        float we = v[j - 1] * e;
        c0.x = c0.x * scale + we * e0.x;  c0.y = c0.y * scale + we * e0.y;
        c0.z = c0.z * scale + we * e0.z;  c0.w = c0.w * scale + we * e0.w;
        c1.x = c1.x * scale + we * e1.x;  c1.y = c1.y * scale + we * e1.y;
        c1.z = c1.z * scale + we * e1.z;  c1.w = c1.w * scale + we * e1.w;
        m = mn;
    }
    float inv = 1.0f / den;
    c0.x *= inv; c0.y *= inv; c0.z *= inv; c0.w *= inv;
    c1.x *= inv; c1.y *= inv; c1.z *= inv; c1.w *= inv;

    size_t ab = (size_t)w * 1024;
    split_store4(Ah + ab +       4 * lane, Al + ab +       4 * lane, n0);
    split_store4(Ah + ab + 256 + 4 * lane, Al + ab + 256 + 4 * lane, n1);
    split_store4(Ah + ab + 512 + 4 * lane, Al + ab + 512 + 4 * lane, c0);
    split_store4(Ah + ab + 768 + 4 * lane, Al + ab + 768 + 4 * lane, c1);

    // prp slice of prop-A panel (written once per (i,b) by h==2/h==4)
    if (h == 2 || h == 4) {
        int pid = inputs_prop[((b * 2 + i) * 3) * 32];
        size_t pr = (size_t)(i * 4096 + b) * 1152;
        float4 p0 = emb4[(size_t)pid * 128 + lane];
        float4 p1 = emb4[(size_t)pid * 128 + 64 + lane];
        split_store4(Aph + pr + 600 + 4 * lane, Apl + pr + 600 + 4 * lane, p0);
        split_store4(Aph + pr + 856 + 4 * lane, Apl + pr + 856 + 4 * lane, p1);
        if (lane < 10) {   // zero-fill K pad [1112,1152)
            ushort4 z = make_ushort4(0, 0, 0, 0);
            *(ushort4*)&Aph[pr + 1112 + 4 * lane] = z;
            *(ushort4*)&Apl[pr + 1112 + 4 * lane] = z;
        }
    }
}

// =============================================================
// Kernel B: pre-split weights to bf16 hi/lo with padding.
// =============================================================
__global__ __launch_bounds__(256) void bsplit_kernel(
    const float* __restrict__ W_out,   // (300,1024)
    const float* __restrict__ W_prop,  // (300,1112)
    unsigned short* __restrict__ Bh,  unsigned short* __restrict__ Bl,   // (320,1024)
    unsigned short* __restrict__ Bph, unsigned short* __restrict__ Bpl)  // (320,1152)
{
    int id = blockIdx.x * 256 + threadIdx.x;
    const int NB1 = 320 * 1024;
    if (id < NB1) {
        int n = id >> 10, k = id & 1023;
        float x = (n < 300) ? W_out[n * 1024 + k] : 0.0f;
        unsigned short h, l; split2(x, h, l);
        Bh[id] = h; Bl[id] = l;
    } else {
        int id2 = id - NB1;
        if (id2 < 320 * 1152) {
            int n = id2 / 1152, k = id2 - n * 1152;
            float x = (n < 300 && k < 1112) ? W_prop[n * 1112 + k] : 0.0f;
            unsigned short h, l; split2(x, h, l);
            Bph[id2] = h; Bpl[id2] = l;
        }
    }
}

// =============================================================
// Split-bf16 MFMA GEMM: C[M,320] = A[M,K] * B[320,K]^T (+bias)
// BM = MF*32, BN=64, BK=64; 4 waves (2x2); wave tile MF*16 x 32.
// EPI=0: head (writes fp32 ent rows + bf16 dom/rng into prop-A)
// EPI=1: prop (writes fp32 prop_out)
// =============================================================
template<int MF, int KTOT, int NSTEP, int EPI>
__global__ __launch_bounds__(256) void gemm_kernel(
    const unsigned short* __restrict__ Agh, const unsigned short* __restrict__ Agl,
    const unsigned short* __restrict__ Bgh, const unsigned short* __restrict__ Bgl,
    const float* __restrict__ bias,
    float* __restrict__ outf,
    unsigned short* __restrict__ Aph, unsigned short* __restrict__ Apl)
{
    constexpr int BM = MF * 32;
    __shared__ unsigned short Ash[BM * 64], Asl[BM * 64];
    __shared__ unsigned short Bsh[64 * 64], Bsl[64 * 64];

    int t = threadIdx.x, lane = t & 63, wid = t >> 6;
    int wm = wid >> 1, wn = wid & 1;
    int m0 = blockIdx.y * BM, n0 = blockIdx.x * 64;

    f32x4 acc[MF][2];
    #pragma unroll
    for (int mf = 0; mf < MF; ++mf)
        #pragma unroll
        for (int nf = 0; nf < 2; ++nf)
            acc[mf][nf] = (f32x4){0.f, 0.f, 0.f, 0.f};

    constexpr int nA  = MF * 4;            // global_load_lds instrs per A buffer
    constexpr int PER = (2 * nA + 16) / 4; // per wave
    int rowq = lane >> 3, cq = lane & 7;

    for (int step = 0; step < NSTEP; ++step) {
        int k0 = step * 64;
        #pragma unroll
        for (int qq = 0; qq < PER; ++qq) {
            int q = wid * PER + qq;
            const unsigned short* src; unsigned short* dst; int j; size_t grow;
            if (q < nA)              { j = q;            src = Agh; dst = Ash; grow = (size_t)m0; }
            else if (q < 2 * nA)     { j = q - nA;       src = Agl; dst = Asl; grow = (size_t)m0; }
            else if (q < 2 * nA + 8) { j = q - 2 * nA;   src = Bgh; dst = Bsh; grow = (size_t)n0; }
            else                     { j = q - 2 * nA - 8; src = Bgl; dst = Bsl; grow = (size_t)n0; }
            size_t ge = (grow + (size_t)(j * 8 + rowq)) * KTOT + k0 + cq * 8;
            gload16(src + ge, dst + j * 512);
        }
        __syncthreads();   // drains vmcnt + barrier (compiler-inserted waitcnt)

        #pragma unroll
        for (int s = 0; s < 2; ++s) {
            int ko = s * 32 + (lane >> 4) * 8;
            s16x8 ah[MF], al[MF], bh[2], bl[2];
            #pragma unroll
            for (int mf = 0; mf < MF; ++mf) {
                int r = (wm * MF + mf) * 16 + (lane & 15);
                ah[mf] = *reinterpret_cast<const s16x8*>(&Ash[r * 64 + ko]);
                al[mf] = *reinterpret_cast<const s16x8*>(&Asl[r * 64 + ko]);
            }
            #pragma unroll
            for (int nf = 0; nf < 2; ++nf) {
                int r = (wn * 2 + nf) * 16 + (lane & 15);
                bh[nf] = *reinterpret_cast<const s16x8*>(&Bsh[r * 64 + ko]);
                bl[nf] = *reinterpret_cast<const s16x8*>(&Bsl[r * 64 + ko]);
            }
            #pragma unroll
            for (int mf = 0; mf < MF; ++mf)
                #pragma unroll
                for (int nf = 0; nf < 2; ++nf) {
                    acc[mf][nf] = __builtin_amdgcn_mfma_f32_16x16x32_bf16(ah[mf], bh[nf], acc[mf][nf], 0, 0, 0);
                    acc[mf][nf] = __builtin_amdgcn_mfma_f32_16x16x32_bf16(ah[mf], bl[nf], acc[mf][nf], 0, 0, 0);
                    acc[mf][nf] = __builtin_amdgcn_mfma_f32_16x16x32_bf16(al[mf], bh[nf], acc[mf][nf], 0, 0, 0);
                }
        }
        __syncthreads();
    }

    // epilogue: C/D layout col = lane&15, row = (lane>>4)*4 + reg
    #pragma unroll
    for (int mf = 0; mf < MF; ++mf)
        #pragma unroll
        for (int nf = 0; nf < 2; ++nf) {
            int n = n0 + wn * 32 + nf * 16 + (lane & 15);
            if (n >= 300) continue;
            int rowbase = m0 + wm * MF * 16 + mf * 16 + ((lane >> 4) << 2);
            float bv = bias[n];
            #pragma unroll
            for (int r = 0; r < 4; ++r) {
                float val = acc[mf][nf][r] + bv;
                int m = rowbase + r;
                if (EPI == 0) {
                    int h = m >> 12;   // block-uniform
                    if (h < 2) {
                        outf[(size_t)m * 300 + n] = val;
                    } else {
                        unsigned short hh, ll; split2(val, hh, ll);
                        int i = (h - 2) >> 1;
                        int col = ((h - 2) & 1) ? 300 + n : n;
                        size_t ar = (size_t)(i * 4096 + (m & 4095)) * 1152 + col;
                        Aph[ar] = hh; Apl[ar] = ll;
                    }
                } else {
                    outf[(size_t)m * 300 + n] = val;
                }
            }
        }
}

// =============================================================
// Kernel D: cosines -> d_out[0:4096]=x_ent, [4096:8192]=x_prop
// =============================================================
__global__ __launch_bounds__(256) void cosine_kernel(
    const float* __restrict__ head_out,  // (8192,300) ent heads
    const float* __restrict__ prop_out,  // (8192,300)
    float* __restrict__ out)             // (8192,)
{
    int w    = blockIdx.x * 4 + (threadIdx.x >> 6);
    int lane = threadIdx.x & 63;
    const float *a, *b;
    if (w < 4096) {
        a = head_out + (size_t)w * 300;
        b = head_out + (size_t)(4096 + w) * 300;
    } else {
        int b2 = w - 4096;
        a = prop_out + (size_t)b2 * 300;
        b = prop_out + (size_t)(4096 + b2) * 300;
    }
    float ab = 0.f, aa = 0.f, bb = 0.f;
    for (int tt = lane; tt < 300; tt += 64) {
        float av = a[tt], bv = b[tt];
        ab += av * bv; aa += av * av; bb += bv * bv;
    }
    #pragma unroll
    for (int d = 1; d < 64; d <<= 1) {
        ab += __shfl_xor(ab, d);
        aa += __shfl_xor(aa, d);
        bb += __shfl_xor(bb, d);
    }
    if (lane == 0) {
        float na = fmaxf(sqrtf(aa), 1e-8f);
        float nb = fmaxf(sqrtf(bb), 1e-8f);
        out[w] = ab / (na * nb);
    }
}

extern "C" void kernel_launch(void* const* d_in, const int* in_sizes, int n_in,
                              void* d_out, int out_size, void* d_ws, size_t ws_size,
                              hipStream_t stream) {
    const int*   inputs      = (const int*)d_in[0];
    const int*   inputs_prop = (const int*)d_in[1];
    const float* emb         = (const float*)d_in[2];
    const float* W_out       = (const float*)d_in[3];
    const float* b_out       = (const float*)d_in[4];
    const float* v           = (const float*)d_in[5];
    const float* W_prop      = (const float*)d_in[6];
    const float* b_prop      = (const float*)d_in[7];
    float* out = (float*)d_out;

    char* ws = (char*)d_ws;
    unsigned short* Ah  = (unsigned short*)(ws + AH_OFF);
    unsigned short* Al  = (unsigned short*)(ws + AL_OFF);
    unsigned short* Aph = (unsigned short*)(ws + APH_OFF);
    unsigned short* Apl = (unsigned short*)(ws + APL_OFF);
    unsigned short* Bh  = (unsigned short*)(ws + BH_OFF);
    unsigned short* Bl  = (unsigned short*)(ws + BL_OFF);
    unsigned short* Bph = (unsigned short*)(ws + BPH_OFF);
    unsigned short* Bpl = (unsigned short*)(ws + BPL_OFF);
    float* head_out = (float*)(ws + HEAD_OFF);
    float* prop_out = (float*)(ws + PROP_OFF);

    attend_kernel<<<6144, 256, 0, stream>>>(inputs, inputs_prop, emb, v, Ah, Al, Aph, Apl);
    bsplit_kernel<<<2720, 256, 0, stream>>>(W_out, W_prop, Bh, Bl, Bph, Bpl);
    gemm_kernel<4, 1024, 16, 0><<<dim3(5, 192), 256, 0, stream>>>(Ah, Al, Bh, Bl, b_out, head_out, Aph, Apl);
    gemm_kernel<2, 1152, 18, 1><<<dim3(5, 128), 256, 0, stream>>>(Aph, Apl, Bph, Bpl, b_prop, prop_out, nullptr, nullptr);
    cosine_kernel<<<2048, 256, 0, stream>>>(head_out, prop_out, out);
}

// Round 3
// 399.035 us; speedup vs baseline: 1.8651x; 1.0010x over previous
//
#include <hip/hip_runtime.h>

typedef short  s16x8 __attribute__((ext_vector_type(8)));
typedef float  f32x4 __attribute__((ext_vector_type(4)));
typedef unsigned short u16x4 __attribute__((ext_vector_type(4)));

// ---------------- workspace layout (bytes) ----------------
#define AH_OFF    0ULL
#define AL_OFF    50331648ULL
#define APH_OFF   100663296ULL
#define APL_OFF   119537664ULL
#define BH_OFF    138412032ULL
#define BL_OFF    139067392ULL
#define BPH_OFF   139722752ULL
#define BPL_OFF   140460032ULL
#define HEAD_OFF  141197312ULL
#define PROP_OFF  151027712ULL   // total 160,858,112

// ---------- fp32 -> bf16 hi/lo split (RNE both) ----------
__device__ __forceinline__ void split2(float x, unsigned short& h, unsigned short& l) {
    unsigned u  = __float_as_uint(x);
    unsigned hb = (u + 0x7FFFu + ((u >> 16) & 1u)) >> 16;
    float hf = __uint_as_float(hb << 16);
    float lf = x - hf;
    unsigned ul = __float_as_uint(lf);
    unsigned lb = (ul + 0x7FFFu + ((ul >> 16) & 1u)) >> 16;
    h = (unsigned short)hb; l = (unsigned short)lb;
}

// nontemporal split-store: keep streaming A-panel writes out of L3 so emb stays resident
__device__ __forceinline__ void split_store4_nt(unsigned short* ph, unsigned short* pl, float4 f) {
    u16x4 h, l;
    split2(f.x, ((unsigned short*)&h)[0], ((unsigned short*)&l)[0]);
    split2(f.y, ((unsigned short*)&h)[1], ((unsigned short*)&l)[1]);
    split2(f.z, ((unsigned short*)&h)[2], ((unsigned short*)&l)[2]);
    split2(f.w, ((unsigned short*)&h)[3], ((unsigned short*)&l)[3]);
    __builtin_nontemporal_store(h, (u16x4*)ph);
    __builtin_nontemporal_store(l, (u16x4*)pl);
}

__device__ __forceinline__ void gload16(const unsigned short* g, unsigned short* l) {
    __builtin_amdgcn_global_load_lds(
        (const __attribute__((address_space(1))) unsigned int*)g,
        (__attribute__((address_space(3))) unsigned int*)l, 16, 0, 0);
}

// =============================================================
// Kernel A: gather + online-softmax attention (deferred rescale,
// 1-deep row prefetch). one wave per (head h in [0,6), b in [0,4096))
// =============================================================
__global__ __launch_bounds__(256) void attend_kernel(
    const int* __restrict__ inputs,        // (4096,2,32)
    const int* __restrict__ inputs_prop,   // (4096,2,3,32)
    const float* __restrict__ emb,         // (100000,512)
    const float* __restrict__ v,           // (31,)
    unsigned short* __restrict__ Ah, unsigned short* __restrict__ Al,
    unsigned short* __restrict__ Aph, unsigned short* __restrict__ Apl)
{
    int w    = blockIdx.x * 4 + (threadIdx.x >> 6);
    int lane = threadIdx.x & 63;
    int h = w >> 12;         // 0..5
    int b = w & 4095;

    int base, i = 0;
    const int* ip;
    if (h < 2) { base = (b * 2 + h) * 32; ip = inputs; }
    else {
        i = (h - 2) >> 1;
        int s = 1 + ((h - 2) & 1);
        base = ((b * 2 + i) * 3 + s) * 32;
        ip = inputs_prop;
    }

    int myidx = 0;
    if (lane < 32) myidx = ip[base + lane];
    int idx0 = __shfl(myidx, 0);

    const float4* emb4 = (const float4*)emb;
    float4 n0 = emb4[(size_t)idx0 * 128 + lane];
    float4 n1 = emb4[(size_t)idx0 * 128 + 64 + lane];

    // prefetch j=1
    int ij1 = __shfl(myidx, 1);
    float4 e0 = emb4[(size_t)ij1 * 128 + lane];
    float4 e1 = emb4[(size_t)ij1 * 128 + 64 + lane];

    float m = -3.0e38f, den = 0.0f;
    float4 c0 = make_float4(0.f, 0.f, 0.f, 0.f);
    float4 c1 = make_float4(0.f, 0.f, 0.f, 0.f);

    for (int j = 1; j < 32; ++j) {
        float4 f0, f1;
        if (j < 31) {                         // prefetch j+1
            int ijn = __shfl(myidx, j + 1);
            f0 = emb4[(size_t)ijn * 128 + lane];
            f1 = emb4[(size_t)ijn * 128 + 64 + lane];
        }
        float p = e0.x * n0.x + e0.y * n0.y + e0.z * n0.z + e0.w * n0.w
                + e1.x * n1.x + e1.y * n1.y + e1.z * n1.z + e1.w * n1.w;
        #pragma unroll
        for (int d = 1; d < 64; d <<= 1) p += __shfl_xor(p, d);

        float s = (p != 0.0f) ? p : -9999.0f;   // mask: scores==0 -> -NEG
        if (s - m > 8.0f) {                     // rare, wave-uniform rescale
            float scale = __expf(m - s);        // m=-3e38 -> 0 on first hit
            den *= scale;
            c0.x *= scale; c0.y *= scale; c0.z *= scale; c0.w *= scale;
            c1.x *= scale; c1.y *= scale; c1.z *= scale; c1.w *= scale;
            m = s;
        }
        float e = __expf(s - m);                // bounded by e^8
        den += e;
        float we = v[j - 1] * e;
        c0.x += we * e0.x;  c0.y += we * e0.y;  c0.z += we * e0.z;  c0.w += we * e0.w;
        c1.x += we * e1.x;  c1.y += we * e1.y;  c1.z += we * e1.z;  c1.w += we * e1.w;
        e0 = f0; e1 = f1;
    }
    float inv = 1.0f / den;
    c0.x *= inv; c0.y *= inv; c0.z *= inv; c0.w *= inv;
    c1.x *= inv; c1.y *= inv; c1.z *= inv; c1.w *= inv;

    size_t ab = (size_t)w * 1024;
    split_store4_nt(Ah + ab +       4 * lane, Al + ab +       4 * lane, n0);
    split_store4_nt(Ah + ab + 256 + 4 * lane, Al + ab + 256 + 4 * lane, n1);
    split_store4_nt(Ah + ab + 512 + 4 * lane, Al + ab + 512 + 4 * lane, c0);
    split_store4_nt(Ah + ab + 768 + 4 * lane, Al + ab + 768 + 4 * lane, c1);

    // prp slice of prop-A panel (written once per (i,b) by h==2/h==4)
    if (h == 2 || h == 4) {
        int pid = inputs_prop[((b * 2 + i) * 3) * 32];
        size_t pr = (size_t)(i * 4096 + b) * 1152;
        float4 p0 = emb4[(size_t)pid * 128 + lane];
        float4 p1 = emb4[(size_t)pid * 128 + 64 + lane];
        split_store4_nt(Aph + pr + 600 + 4 * lane, Apl + pr + 600 + 4 * lane, p0);
        split_store4_nt(Aph + pr + 856 + 4 * lane, Apl + pr + 856 + 4 * lane, p1);
        if (lane < 10) {   // zero-fill K pad [1112,1152)
            u16x4 z = (u16x4){0, 0, 0, 0};
            __builtin_nontemporal_store(z, (u16x4*)&Aph[pr + 1112 + 4 * lane]);
            __builtin_nontemporal_store(z, (u16x4*)&Apl[pr + 1112 + 4 * lane]);
        }
    }
}

// =============================================================
// Kernel B: pre-split weights to bf16 hi/lo with padding.
// =============================================================
__global__ __launch_bounds__(256) void bsplit_kernel(
    const float* __restrict__ W_out,   // (300,1024)
    const float* __restrict__ W_prop,  // (300,1112)
    unsigned short* __restrict__ Bh,  unsigned short* __restrict__ Bl,   // (320,1024)
    unsigned short* __restrict__ Bph, unsigned short* __restrict__ Bpl)  // (320,1152)
{
    int id = blockIdx.x * 256 + threadIdx.x;
    const int NB1 = 320 * 1024;
    if (id < NB1) {
        int n = id >> 10, k = id & 1023;
        float x = (n < 300) ? W_out[n * 1024 + k] : 0.0f;
        unsigned short h, l; split2(x, h, l);
        Bh[id] = h; Bl[id] = l;
    } else {
        int id2 = id - NB1;
        if (id2 < 320 * 1152) {
            int n = id2 / 1152, k = id2 - n * 1152;
            float x = (n < 300 && k < 1112) ? W_prop[n * 1112 + k] : 0.0f;
            unsigned short h, l; split2(x, h, l);
            Bph[id2] = h; Bpl[id2] = l;
        }
    }
}

// =============================================================
// Split-bf16 MFMA GEMM: C[M,320] = A[M,K] * B[320,K]^T (+bias)
// BM = MF*32, BN=64, BK=64; 4 waves (2x2); wave tile MF*16 x 32.
// EPI=0: head (writes fp32 ent rows + bf16 dom/rng into prop-A)
// EPI=1: prop (writes fp32 prop_out)
// =============================================================
template<int MF, int KTOT, int NSTEP, int EPI>
__global__ __launch_bounds__(256) void gemm_kernel(
    const unsigned short* __restrict__ Agh, const unsigned short* __restrict__ Agl,
    const unsigned short* __restrict__ Bgh, const unsigned short* __restrict__ Bgl,
    const float* __restrict__ bias,
    float* __restrict__ outf,
    unsigned short* __restrict__ Aph, unsigned short* __restrict__ Apl)
{
    constexpr int BM = MF * 32;
    __shared__ unsigned short Ash[BM * 64], Asl[BM * 64];
    __shared__ unsigned short Bsh[64 * 64], Bsl[64 * 64];

    int t = threadIdx.x, lane = t & 63, wid = t >> 6;
    int wm = wid >> 1, wn = wid & 1;
    int m0 = blockIdx.y * BM, n0 = blockIdx.x * 64;

    f32x4 acc[MF][2];
    #pragma unroll
    for (int mf = 0; mf < MF; ++mf)
        #pragma unroll
        for (int nf = 0; nf < 2; ++nf)
            acc[mf][nf] = (f32x4){0.f, 0.f, 0.f, 0.f};

    constexpr int nA  = MF * 4;            // global_load_lds instrs per A buffer
    constexpr int PER = (2 * nA + 16) / 4; // per wave
    int rowq = lane >> 3, cq = lane & 7;

    for (int step = 0; step < NSTEP; ++step) {
        int k0 = step * 64;
        #pragma unroll
        for (int qq = 0; qq < PER; ++qq) {
            int q = wid * PER + qq;
            const unsigned short* src; unsigned short* dst; int j; size_t grow;
            if (q < nA)              { j = q;            src = Agh; dst = Ash; grow = (size_t)m0; }
            else if (q < 2 * nA)     { j = q - nA;       src = Agl; dst = Asl; grow = (size_t)m0; }
            else if (q < 2 * nA + 8) { j = q - 2 * nA;   src = Bgh; dst = Bsh; grow = (size_t)n0; }
            else                     { j = q - 2 * nA - 8; src = Bgl; dst = Bsl; grow = (size_t)n0; }
            size_t ge = (grow + (size_t)(j * 8 + rowq)) * KTOT + k0 + cq * 8;
            gload16(src + ge, dst + j * 512);
        }
        __syncthreads();   // drains vmcnt + barrier (compiler-inserted waitcnt)

        #pragma unroll
        for (int s = 0; s < 2; ++s) {
            int ko = s * 32 + (lane >> 4) * 8;
            s16x8 ah[MF], al[MF], bh[2], bl[2];
            #pragma unroll
            for (int mf = 0; mf < MF; ++mf) {
                int r = (wm * MF + mf) * 16 + (lane & 15);
                ah[mf] = *reinterpret_cast<const s16x8*>(&Ash[r * 64 + ko]);
                al[mf] = *reinterpret_cast<const s16x8*>(&Asl[r * 64 + ko]);
            }
            #pragma unroll
            for (int nf = 0; nf < 2; ++nf) {
                int r = (wn * 2 + nf) * 16 + (lane & 15);
                bh[nf] = *reinterpret_cast<const s16x8*>(&Bsh[r * 64 + ko]);
                bl[nf] = *reinterpret_cast<const s16x8*>(&Bsl[r * 64 + ko]);
            }
            #pragma unroll
            for (int mf = 0; mf < MF; ++mf)
                #pragma unroll
                for (int nf = 0; nf < 2; ++nf) {
                    acc[mf][nf] = __builtin_amdgcn_mfma_f32_16x16x32_bf16(ah[mf], bh[nf], acc[mf][nf], 0, 0, 0);
                    acc[mf][nf] = __builtin_amdgcn_mfma_f32_16x16x32_bf16(ah[mf], bl[nf], acc[mf][nf], 0, 0, 0);
                    acc[mf][nf] = __builtin_amdgcn_mfma_f32_16x16x32_bf16(al[mf], bh[nf], acc[mf][nf], 0, 0, 0);
                }
        }
        __syncthreads();
    }

    // epilogue: C/D layout col = lane&15, row = (lane>>4)*4 + reg
    #pragma unroll
    for (int mf = 0; mf < MF; ++mf)
        #pragma unroll
        for (int nf = 0; nf < 2; ++nf) {
            int n = n0 + wn * 32 + nf * 16 + (lane & 15);
            if (n >= 300) continue;
            int rowbase = m0 + wm * MF * 16 + mf * 16 + ((lane >> 4) << 2);
            float bv = bias[n];
            #pragma unroll
            for (int r = 0; r < 4; ++r) {
                float val = acc[mf][nf][r] + bv;
                int m = rowbase + r;
                if (EPI == 0) {
                    int h = m >> 12;   // block-uniform
                    if (h < 2) {
                        outf[(size_t)m * 300 + n] = val;
                    } else {
                        unsigned short hh, ll; split2(val, hh, ll);
                        int i = (h - 2) >> 1;
                        int col = ((h - 2) & 1) ? 300 + n : n;
                        size_t ar = (size_t)(i * 4096 + (m & 4095)) * 1152 + col;
                        Aph[ar] = hh; Apl[ar] = ll;
                    }
                } else {
                    outf[(size_t)m * 300 + n] = val;
                }
            }
        }
}

// =============================================================
// Kernel D: cosines -> d_out[0:4096]=x_ent, [4096:8192]=x_prop
// =============================================================
__global__ __launch_bounds__(256) void cosine_kernel(
    const float* __restrict__ head_out,  // (8192,300) ent heads
    const float* __restrict__ prop_out,  // (8192,300)
    float* __restrict__ out)             // (8192,)
{
    int w    = blockIdx.x * 4 + (threadIdx.x >> 6);
    int lane = threadIdx.x & 63;
    const float *a, *b;
    if (w < 4096) {
        a = head_out + (size_t)w * 300;
        b = head_out + (size_t)(4096 + w) * 300;
    } else {
        int b2 = w - 4096;
        a = prop_out + (size_t)b2 * 300;
        b = prop_out + (size_t)(4096 + b2) * 300;
    }
    float ab = 0.f, aa = 0.f, bb = 0.f;
    for (int tt = lane; tt < 300; tt += 64) {
        float av = a[tt], bv = b[tt];
        ab += av * bv; aa += av * av; bb += bv * bv;
    }
    #pragma unroll
    for (int d = 1; d < 64; d <<= 1) {
        ab += __shfl_xor(ab, d);
        aa += __shfl_xor(aa, d);
        bb += __shfl_xor(bb, d);
    }
    if (lane == 0) {
        float na = fmaxf(sqrtf(aa), 1e-8f);
        float nb = fmaxf(sqrtf(bb), 1e-8f);
        out[w] = ab / (na * nb);
    }
}

extern "C" void kernel_launch(void* const* d_in, const int* in_sizes, int n_in,
                              void* d_out, int out_size, void* d_ws, size_t ws_size,
                              hipStream_t stream) {
    const int*   inputs      = (const int*)d_in[0];
    const int*   inputs_prop = (const int*)d_in[1];
    const float* emb         = (const float*)d_in[2];
    const float* W_out       = (const float*)d_in[3];
    const float* b_out       = (const float*)d_in[4];
    const float* v           = (const float*)d_in[5];
    const float* W_prop      = (const float*)d_in[6];
    const float* b_prop      = (const float*)d_in[7];
    float* out = (float*)d_out;

    char* ws = (char*)d_ws;
    unsigned short* Ah  = (unsigned short*)(ws + AH_OFF);
    unsigned short* Al  = (unsigned short*)(ws + AL_OFF);
    unsigned short* Aph = (unsigned short*)(ws + APH_OFF);
    unsigned short* Apl = (unsigned short*)(ws + APL_OFF);
    unsigned short* Bh  = (unsigned short*)(ws + BH_OFF);
    unsigned short* Bl  = (unsigned short*)(ws + BL_OFF);
    unsigned short* Bph = (unsigned short*)(ws + BPH_OFF);
    unsigned short* Bpl = (unsigned short*)(ws + BPL_OFF);
    float* head_out = (float*)(ws + HEAD_OFF);
    float* prop_out = (float*)(ws + PROP_OFF);

    attend_kernel<<<6144, 256, 0, stream>>>(inputs, inputs_prop, emb, v, Ah, Al, Aph, Apl);
    bsplit_kernel<<<2720, 256, 0, stream>>>(W_out, W_prop, Bh, Bl, Bph, Bpl);
    gemm_kernel<4, 1024, 16, 0><<<dim3(5, 192), 256, 0, stream>>>(Ah, Al, Bh, Bl, b_out, head_out, Aph, Apl);
    gemm_kernel<2, 1152, 18, 1><<<dim3(5, 128), 256, 0, stream>>>(Aph, Apl, Bph, Bpl, b_prop, prop_out, nullptr, nullptr);
    cosine_kernel<<<2048, 256, 0, stream>>>(head_out, prop_out, out);
}